// Round 7
// baseline (184.317 us; speedup 1.0000x reference)
//
#include <hip/hip_runtime.h>

#define NN 100000
#define NE 1600000
#define C 32

#define SHIFT 8
#define BINW 256                              // nodes per bin
#define NBIN ((NN + BINW - 1) / BINW)         // 391
#define EPB 8192                              // edges per block (binning)
#define NCHK ((NE + EPB - 1) / EPB)           // 196 chunks = k_bin blocks
#define SLACK 56                              // slots per (chunk,bin); lambda~21, max~43
#define CAPT (NCHK * SLACK)                   // 10976 tmp slots per bin
#define SCAP 5120                             // LDS sorted-list capacity (4096+16sigma)

__device__ __forceinline__ unsigned bf16rne(float f) {
    unsigned u = __float_as_uint(f);
    return (u + 0x7fffu + ((u >> 16) & 1u)) >> 16;
}
__device__ __forceinline__ float blo(unsigned u) { return __uint_as_float(u << 16); }
__device__ __forceinline__ float bhi(unsigned u) { return __uint_as_float(u & 0xffff0000u); }

// ---------------- kernels ----------------

// zero per-node degree (ws is poisoned each iter)
__global__ __launch_bounds__(256) void k_init(int* __restrict__ deg) {
    int i = blockIdx.x * 256 + threadIdx.x;
    if (i < NN) deg[i] = 0;
}

// single-pass scatter into chunk-partitioned bins + global per-node degree.
// Block b statically owns slots [bin*CAPT + b*SLACK, +SLACK) of every bin:
// no histogram pass, no scans, no claim atomics.
__global__ __launch_bounds__(256) void k_bin(const int* __restrict__ ei,
                                             int* __restrict__ tmp,
                                             int* __restrict__ cfill,
                                             int* __restrict__ deg) {
    __shared__ int lcur[NBIN];
    int b = blockIdx.x, t = threadIdx.x;
    for (int i = t; i < NBIN; i += 256) lcur[i] = i * CAPT + b * SLACK;
    __syncthreads();
    int e0 = b * EPB, e1 = min(e0 + EPB, NE);   // windows %4 == 0
    const int4* src4 = (const int4*)ei;
    const int4* col4 = (const int4*)(ei + NE);
    for (int q = (e0 >> 2) + t; q < (e1 >> 2); q += 256) {
        int4 s = src4[q];
        int4 c = col4[q];
        int p0 = atomicAdd(&lcur[c.x >> SHIFT], 1);
        tmp[p0] = (s.x << SHIFT) | (c.x & (BINW - 1));
        int p1 = atomicAdd(&lcur[c.y >> SHIFT], 1);
        tmp[p1] = (s.y << SHIFT) | (c.y & (BINW - 1));
        int p2 = atomicAdd(&lcur[c.z >> SHIFT], 1);
        tmp[p2] = (s.z << SHIFT) | (c.z & (BINW - 1));
        int p3 = atomicAdd(&lcur[c.w >> SHIFT], 1);
        tmp[p3] = (s.w << SHIFT) | (c.w & (BINW - 1));
        atomicAdd(&deg[c.x], 1);                // fire-and-forget L2 atomics
        atomicAdd(&deg[c.y], 1);
        atomicAdd(&deg[c.z], 1);
        atomicAdd(&deg[c.w], 1);
    }
    __syncthreads();
    for (int i = t; i < NBIN; i += 256)                       // chunk fills
        cfill[i * NCHK + b] = lcur[i] - (i * CAPT + b * SLACK);
}

// h' = bf16( dinv * (x @ W^T) ), packed 2 channels/uint -> 64B rows.
__global__ __launch_bounds__(256) void k_linear(const float* __restrict__ x,
                                                const float* __restrict__ W,
                                                const int* __restrict__ deg,
                                                unsigned* __restrict__ hu) {
    __shared__ float Ws[C][C + 1];
    __shared__ float xs[16][C];
    int t = threadIdx.x;
    for (int i = t; i < C * C; i += 256)
        Ws[i / C][i % C] = W[i];

    int node0 = blockIdx.x * 16;
#pragma unroll
    for (int i = t; i < 16 * C; i += 256) {
        int idx = node0 * C + i;     // coalesced load of 16 rows
        xs[i >> 5][i & 31] = (idx < NN * C) ? x[idx] : 0.0f;
    }
    __syncthreads();
    int lnode = t >> 4, m = t & 15;
    int node = node0 + lnode;
    if (node < NN) {
        float a0 = 0.0f, a1 = 0.0f;
#pragma unroll
        for (int k = 0; k < C; ++k) {
            float xv = xs[lnode][k];
            a0 += xv * Ws[2 * m][k];
            a1 += xv * Ws[2 * m + 1][k];
        }
        float d = rsqrtf(1.0f + (float)deg[node]);   // deg incl. self-loop
        hu[node * 16 + m] = bf16rne(a0 * d) | (bf16rne(a1 * d) << 16);
    }
}

// fused place+aggregate: one block per bin. Count gapped segment -> wave
// scan -> place sorted edge list in LDS -> 8-lane-group-per-node register
// gather (no shuffles, no srt/off/dinv globals, one dispatch).
#define AGG_T 1024
__global__ __launch_bounds__(AGG_T) void k_placeAgg(const int* __restrict__ cfill,
                                                    const int* __restrict__ tmp,
                                                    const uint2* __restrict__ hu2,
                                                    const float* __restrict__ b,
                                                    float* __restrict__ out) {
    __shared__ int ccnt[NCHK];
    __shared__ int lcnt[BINW];
    __shared__ int lbase[BINW];
    __shared__ int lcur[BINW];
    __shared__ int lsort[SCAP];               // ~20KB; total LDS ~24.4KB
    __shared__ int wtot[4], wbase[4];
    int bin = blockIdx.x, t = threadIdx.x;
    if (t < NCHK) ccnt[t] = cfill[bin * NCHK + t];
    if (t < BINW) lcnt[t] = 0;
    __syncthreads();
    int gb = bin * CAPT;
    // phase A: count valid slots of the gapped segment
    for (int s = t; s < CAPT; s += AGG_T) {
        int chunk = s / SLACK;                 // magic-mul division
        int o = s - chunk * SLACK;
        if (o < ccnt[chunk])
            atomicAdd(&lcnt[tmp[gb + s] & (BINW - 1)], 1);
    }
    __syncthreads();
    // phase B: exclusive scan of 256 counts (threads 0..255 = waves 0..3)
    int lane = t & 63, w4 = t >> 6;
    int cv = 0, v = 0;
    if (t < BINW) {
        cv = lcnt[t];
        v = cv;
#pragma unroll
        for (int d = 1; d < 64; d <<= 1) {
            int u = __shfl_up(v, d);
            if (lane >= d) v += u;
        }
        if (lane == 63) wtot[w4] = v;
    }
    __syncthreads();
    if (t == 0) {
        int r = 0;
#pragma unroll
        for (int k = 0; k < 4; ++k) { wbase[k] = r; r += wtot[k]; }
    }
    __syncthreads();
    if (t < BINW) {
        int loc = wbase[w4] + v - cv;          // exclusive local offset
        lbase[t] = loc;
        lcur[t] = loc;
    }
    __syncthreads();
    // phase C: place into LDS sorted list (tmp re-read is L2-hot)
    for (int s = t; s < CAPT; s += AGG_T) {
        int chunk = s / SLACK;
        int o = s - chunk * SLACK;
        if (o < ccnt[chunk]) {
            int e = tmp[gb + s];
            int pos = atomicAdd(&lcur[e & (BINW - 1)], 1);
            lsort[pos] = e >> SHIFT;
        }
    }
    __syncthreads();
    // phase D: gather. 8-lane group per node; edges contiguous in lsort.
    int G = t >> 3, m = t & 7;                 // 128 groups, channels 4m..4m+3
#pragma unroll
    for (int rr = 0; rr < 2; ++rr) {
        int loc = G + rr * 128;
        int node = (bin << SHIFT) + loc;
        int beg = lbase[loc], cnt = lcnt[loc];
        float s0 = 0.0f, s1 = 0.0f, s2 = 0.0f, s3 = 0.0f;
        int j = beg, jend = beg + cnt;
        for (; j + 3 < jend; j += 4) {         // 4 rows in flight per group
            int r0 = lsort[j], r1 = lsort[j + 1], r2 = lsort[j + 2], r3 = lsort[j + 3];
            uint2 u0 = hu2[r0 * 8 + m];
            uint2 u1 = hu2[r1 * 8 + m];
            uint2 u2 = hu2[r2 * 8 + m];
            uint2 u3 = hu2[r3 * 8 + m];
            s0 += blo(u0.x); s1 += bhi(u0.x); s2 += blo(u0.y); s3 += bhi(u0.y);
            s0 += blo(u1.x); s1 += bhi(u1.x); s2 += blo(u1.y); s3 += bhi(u1.y);
            s0 += blo(u2.x); s1 += bhi(u2.x); s2 += blo(u2.y); s3 += bhi(u2.y);
            s0 += blo(u3.x); s1 += bhi(u3.x); s2 += blo(u3.y); s3 += bhi(u3.y);
        }
        for (; j < jend; ++j) {
            uint2 u = hu2[lsort[j] * 8 + m];
            s0 += blo(u.x); s1 += bhi(u.x); s2 += blo(u.y); s3 += bhi(u.y);
        }
        if (node < NN) {
            float dn = rsqrtf(1.0f + (float)cnt);
            uint2 us = hu2[node * 8 + m];      // self-loop row (pre-scaled)
            float4 bb = ((const float4*)b)[m];
            float o0 = bb.x + dn * (s0 + blo(us.x));
            float o1 = bb.y + dn * (s1 + bhi(us.x));
            float o2 = bb.z + dn * (s2 + blo(us.y));
            float o3 = bb.w + dn * (s3 + bhi(us.y));
            ((float4*)out)[node * 8 + m] = make_float4(o0, o1, o2, o3);
        }
    }
}

// ---------------- launch ----------------

extern "C" void kernel_launch(void* const* d_in, const int* in_sizes, int n_in,
                              void* d_out, int out_size, void* d_ws, size_t ws_size,
                              hipStream_t stream) {
    const float* x  = (const float*)d_in[0];
    const int*   ei = (const int*)d_in[1];
    const float* W  = (const float*)d_in[2];
    const float* b  = (const float*)d_in[3];
    float* out = (float*)d_out;

    // ws (~24 MB of 256 MB pool) — no overlays, all buffers distinct
    char* ws = (char*)d_ws;
    size_t o = 0;
    int*      tmp   = (int*)(ws + o);      o += (size_t)NBIN * CAPT * 4;   o = (o + 255) & ~(size_t)255;
    unsigned* hu    = (unsigned*)(ws + o); o += (size_t)NN * 16 * 4;       o = (o + 255) & ~(size_t)255;
    int*      cfill = (int*)(ws + o);      o += (size_t)NBIN * NCHK * 4;   o = (o + 255) & ~(size_t)255;
    int*      deg   = (int*)(ws + o);

    k_init<<<(NN + 255) / 256, 256, 0, stream>>>(deg);
    k_bin<<<NCHK, 256, 0, stream>>>(ei, tmp, cfill, deg);
    k_linear<<<(NN + 15) / 16, 256, 0, stream>>>(x, W, deg, hu);
    k_placeAgg<<<NBIN, AGG_T, 0, stream>>>(cfill, tmp, (const uint2*)hu, b, out);
}